// Round 1
// baseline (209.490 us; speedup 1.0000x reference)
//
#include <hip/hip_runtime.h>
#include <hip/hip_bf16.h>

// SegmentDeactivation: KAN layer with masked linear fallback.
// Strategy: fold everything into one bf16 GEMM over packed K = 512*36 (spline,
// dense-ified 4-sparse bases) + 512 (silu(x) x base_weight) + 512 (x x masked slope a),
// plus a per-o bias (sum of masked intercepts b_lin) initialized into d_out.
// GEMM: M=1024, N=512, K=19456, 128x128 tile, BK=32, 16x16x32 bf16 MFMA,
// global_load_lds staging (m97 structure), split-K=16 with fp32 atomicAdd epilogue.

typedef unsigned short u16;
typedef unsigned int u32;
typedef __attribute__((ext_vector_type(4))) unsigned short u16x4;
typedef __attribute__((ext_vector_type(8))) short short8;
typedef __attribute__((ext_vector_type(4))) float floatx4;

#define IN_F 512
#define OUT_F 512
#define BATCH 1024
#define C_PAD 36
#define K_SPLINE (IN_F * C_PAD)      // 18432
#define K_BASE_OFF K_SPLINE          // silu(x) * base_weight cols
#define K_LIN_OFF (K_SPLINE + IN_F)  // x * Am cols
#define K_TOT (K_SPLINE + IN_F + IN_F)  // 19456
#define SPLITS 16
#define KPS (K_TOT / SPLITS)         // 1216
#define KIT (KPS / 32)               // 38

static __device__ inline u16 f2b(float f) {
  union { float f; u32 u; } v; v.f = f;
  u32 r = v.u + 0x7FFFu + ((v.u >> 16) & 1u);  // round-nearest-even
  return (u16)(r >> 16);
}

// ---- mask dtype detector: int32 (flags=0) / uint8-bool (flags&1) / float32 (flags&2)
__global__ void detect_mask_kernel(const u32* __restrict__ m, int* __restrict__ flags) {
  int id = blockIdx.x * blockDim.x + threadIdx.x;  // 65536 threads -> 256KB scanned
  u32 w = m[id];
  if (w == 0x3F800000u) atomicOr(flags, 2);
  else if (w & 0xFFFFFF00u) atomicOr(flags, 1);
}

// ---- pack B: [o][k] bf16 rows; also per-o bias accumulation
__global__ void pack_b_kernel(const float* __restrict__ bw, const float* __restrict__ sw,
                              const float* __restrict__ sc, const void* __restrict__ maskp,
                              const int* __restrict__ flags, u16* __restrict__ B,
                              float* __restrict__ bias) {
  int id = blockIdx.x * blockDim.x + threadIdx.x;  // 262144 = o*512+i
  int o = id >> 9, i = id & 511;
  int fl = *flags;
  bool mk;
  if (fl & 2)      mk = ((const float*)maskp)[id] != 0.0f;
  else if (fl & 1) mk = ((const unsigned char*)maskp)[id] != 0;
  else             mk = ((const int*)maskp)[id] != 0;

  float s = sc[id];
  const float* wrow = sw + (size_t)id * 35;
  float w[35];
#pragma unroll
  for (int c = 0; c < 35; ++c) w[c] = wrow[c] * s;

  // spline values at grid endpoints x=-1 (t=0, cells 0..2) and x=+1 (cells 32..34)
  float ys = (w[0] + 4.0f * w[1] + w[2]) * (1.0f / 6.0f);
  float ye = (w[32] + 4.0f * w[33] + w[34]) * (1.0f / 6.0f);
  float a = (ye - ys) * 0.5f;   // dx = 2 exactly
  float bl = ys + a;            // b = y_start - a*gmin, gmin=-1

  u16 row[C_PAD];
#pragma unroll
  for (int c = 0; c < 35; ++c) row[c] = f2b(mk ? 0.0f : w[c]);
  row[35] = 0;

  size_t base = (size_t)o * K_TOT + (size_t)i * C_PAD;
#pragma unroll
  for (int q = 0; q < 9; ++q)
    *reinterpret_cast<u16x4*>(B + base + q * 4) = *reinterpret_cast<u16x4*>(row + q * 4);

  B[(size_t)o * K_TOT + K_BASE_OFF + i] = f2b(bw[id]);
  B[(size_t)o * K_TOT + K_LIN_OFF + i] = f2b(mk ? a : 0.0f);
  if (mk) atomicAdd(&bias[o], bl);
}

// ---- pack A: [b][k] bf16 rows: dense-ified bases + silu(x) + x
__global__ void pack_a_kernel(const float* __restrict__ x, u16* __restrict__ A) {
  int id = blockIdx.x * blockDim.x + threadIdx.x;  // 524288 = b*512+i
  int b = id >> 9, i = id & 511;
  float xv = x[id];

  int m = (int)floorf((xv + 1.1875f) * 16.0f);
  float gm = (float)m * 0.0625f - 1.1875f;
  if (xv < gm) { m -= 1; gm -= 0.0625f; }
  else if (xv >= gm + 0.0625f) { m += 1; gm += 0.0625f; }

  bool ok = (m >= 0) && (m <= 37);
  float B0 = 0.f, B1 = 0.f, B2 = 0.f, B3 = 0.f;
  if (ok) {
    float t = (xv - gm) * 16.0f;
    float t2 = t * t, t3 = t2 * t;
    float omt = 1.0f - t;
    B0 = omt * omt * omt * (1.0f / 6.0f);
    B1 = (3.0f * t3 - 6.0f * t2 + 4.0f) * (1.0f / 6.0f);
    B2 = (-3.0f * t3 + 3.0f * t2 + 3.0f * t + 1.0f) * (1.0f / 6.0f);
    B3 = t3 * (1.0f / 6.0f);
  }

  u16 row[C_PAD];
#pragma unroll
  for (int c = 0; c < C_PAD; ++c) {
    float v = 0.0f;
    if (ok && c <= 34) {          // basis indices valid range 0..34 (35 bases)
      if (c == m - 3) v = B0;
      else if (c == m - 2) v = B1;
      else if (c == m - 1) v = B2;
      else if (c == m) v = B3;
    }
    row[c] = f2b(v);
  }
  size_t base = (size_t)b * K_TOT + (size_t)i * C_PAD;
#pragma unroll
  for (int q = 0; q < 9; ++q)
    *reinterpret_cast<u16x4*>(A + base + q * 4) = *reinterpret_cast<u16x4*>(row + q * 4);

  float sl = xv / (1.0f + __expf(-xv));  // silu
  A[(size_t)b * K_TOT + K_BASE_OFF + i] = f2b(sl);
  A[(size_t)b * K_TOT + K_LIN_OFF + i] = f2b(xv);
}

// ---- init d_out with per-o bias
__global__ void init_out_kernel(const float* __restrict__ bias, float* __restrict__ out) {
  int id = blockIdx.x * blockDim.x + threadIdx.x;  // 524288
  out[id] = bias[id & 511];
}

// ---- split-K GEMM, 128x128 tile, BK=32, mfma_f32_16x16x32_bf16
__global__ __launch_bounds__(256) void gemm_kernel(const u16* __restrict__ A,
                                                   const u16* __restrict__ Bp,
                                                   float* __restrict__ out) {
  __shared__ u16 As[128 * 32];
  __shared__ u16 Bs[128 * 32];
  int t = threadIdx.x;
  int bm = blockIdx.x, bn = blockIdx.y, ks = blockIdx.z;
  int w = t >> 6, l = t & 63;
  int wm = w & 1, wn = w >> 1;

  floatx4 acc[4][4];
#pragma unroll
  for (int p = 0; p < 4; ++p)
#pragma unroll
    for (int q = 0; q < 4; ++q) acc[p][q] = (floatx4)0.0f;

  int ra = t >> 2;            // staging row 0..63
  int cb = (t & 3) << 3;      // element offset within 32-elem slab: 0,8,16,24
  const u16* Ag = A + (size_t)(bm * 128 + ra) * K_TOT + (size_t)ks * KPS + cb;
  const u16* Bg = Bp + (size_t)(bn * 128 + ra) * K_TOT + (size_t)ks * KPS + cb;
  u16* Asp = &As[ra * 32 + cb];
  u16* Bsp = &Bs[ra * 32 + cb];

  for (int kk = 0; kk < KIT; ++kk) {
    __builtin_amdgcn_global_load_lds((const __attribute__((address_space(1))) void*)Ag,
                                     (__attribute__((address_space(3))) void*)Asp, 16, 0, 0);
    __builtin_amdgcn_global_load_lds((const __attribute__((address_space(1))) void*)(Ag + (size_t)64 * K_TOT),
                                     (__attribute__((address_space(3))) void*)(Asp + 64 * 32), 16, 0, 0);
    __builtin_amdgcn_global_load_lds((const __attribute__((address_space(1))) void*)Bg,
                                     (__attribute__((address_space(3))) void*)Bsp, 16, 0, 0);
    __builtin_amdgcn_global_load_lds((const __attribute__((address_space(1))) void*)(Bg + (size_t)64 * K_TOT),
                                     (__attribute__((address_space(3))) void*)(Bsp + 64 * 32), 16, 0, 0);
    Ag += 32; Bg += 32;
    __syncthreads();

    short8 af[4], bf[4];
    int mr = l & 15;
    int kq = (l >> 4) << 3;
#pragma unroll
    for (int tm = 0; tm < 4; ++tm)
      af[tm] = *(const short8*)&As[(wm * 64 + tm * 16 + mr) * 32 + kq];
#pragma unroll
    for (int tn = 0; tn < 4; ++tn)
      bf[tn] = *(const short8*)&Bs[(wn * 64 + tn * 16 + mr) * 32 + kq];
#pragma unroll
    for (int tm = 0; tm < 4; ++tm)
#pragma unroll
      for (int tn = 0; tn < 4; ++tn)
        acc[tm][tn] = __builtin_amdgcn_mfma_f32_16x16x32_bf16(af[tm], bf[tn], acc[tm][tn], 0, 0, 0);
    __syncthreads();
  }

  // epilogue: C/D layout col=lane&15 (n), row=(lane>>4)*4+reg (m)
  int r0 = bm * 128 + wm * 64 + ((l >> 4) << 2);
  int c0 = bn * 128 + wn * 64 + (l & 15);
#pragma unroll
  for (int tm = 0; tm < 4; ++tm)
#pragma unroll
    for (int tn = 0; tn < 4; ++tn)
#pragma unroll
      for (int r = 0; r < 4; ++r)
        atomicAdd(&out[(size_t)(r0 + tm * 16 + r) * OUT_F + c0 + tn * 16], acc[tm][tn][r]);
}

extern "C" void kernel_launch(void* const* d_in, const int* in_sizes, int n_in,
                              void* d_out, int out_size, void* d_ws, size_t ws_size,
                              hipStream_t stream) {
  const float* x  = (const float*)d_in[0];
  const float* bw = (const float*)d_in[1];
  const float* sw = (const float*)d_in[2];
  const float* sc = (const float*)d_in[3];
  // d_in[4] = grid: uniform, h=1/16 over extended knots (n-3)/16 - 1; constants baked in.
  const void* mask = d_in[5];

  const size_t A_BYTES = (size_t)BATCH * K_TOT * 2;   // 39,845,888
  const size_t B_BYTES = (size_t)OUT_F * K_TOT * 2;   // 19,922,944
  char* wsb = (char*)d_ws;
  u16* Apack = (u16*)wsb;
  u16* Bpack = (u16*)(wsb + A_BYTES);
  size_t BIAS_OFF = A_BYTES + B_BYTES;
  float* bias = (float*)(wsb + BIAS_OFF);
  int* flags = (int*)(wsb + BIAS_OFF + 2048);

  hipMemsetAsync(wsb + BIAS_OFF, 0, 2048 + 64, stream);
  detect_mask_kernel<<<256, 256, 0, stream>>>((const u32*)mask, flags);
  pack_b_kernel<<<1024, 256, 0, stream>>>(bw, sw, sc, mask, flags, Bpack, bias);
  pack_a_kernel<<<2048, 256, 0, stream>>>(x, Apack);
  init_out_kernel<<<2048, 256, 0, stream>>>(bias, (float*)d_out);
  gemm_kernel<<<dim3(8, 4, SPLITS), 256, 0, stream>>>(Apack, Bpack, (float*)d_out);
}

// Round 2
// 178.176 us; speedup vs baseline: 1.1758x; 1.1758x over previous
//
#include <hip/hip_runtime.h>
#include <hip/hip_bf16.h>

// SegmentDeactivation: KAN layer folded into one bf16 GEMM.
// K = 512*36 (dense-ified 4-sparse cubic B-spline bases) + 512 (silu(x)·W_base)
//   + 512 (x·masked-slope), bias = sum of masked intercepts.
// R2: coalesced LDS-staged pack kernels; SPLITS=32 split-K with fp32 partials
//     + reduce (no atomics); ks-grouped block decode for per-XCD L2 locality.

typedef unsigned short u16;
typedef unsigned int u32;
typedef unsigned long long u64;
typedef __attribute__((ext_vector_type(8))) short short8;
typedef __attribute__((ext_vector_type(4))) float floatx4;

#define IN_F 512
#define OUT_F 512
#define BATCH 1024
#define C_PAD 36
#define K_SPLINE (IN_F * C_PAD)         // 18432
#define K_BASE_OFF K_SPLINE
#define K_LIN_OFF (K_SPLINE + IN_F)
#define K_TOT (K_SPLINE + IN_F + IN_F)  // 19456
#define SPLITS 32
#define KPS (K_TOT / SPLITS)            // 608
#define KIT (KPS / 32)                  // 19
#define MN (BATCH * OUT_F)              // 524288

static __device__ inline u16 f2b(float f) {
  union { float f; u32 u; } v; v.f = f;
  u32 r = v.u + 0x7FFFu + ((v.u >> 16) & 1u);  // round-nearest-even
  return (u16)(r >> 16);
}

// ---- mask dtype detector: int32 (flags=0) / uint8-bool (flags&1) / float32 (flags&2)
__global__ void detect_mask_kernel(const u32* __restrict__ m, int* __restrict__ flags) {
  int id = blockIdx.x * blockDim.x + threadIdx.x;  // 65536 words = 256KB scanned
  u32 w = m[id];
  if (w == 0x3F800000u) atomicOr(flags, 2);
  else if (w & 0xFFFFFF00u) atomicOr(flags, 1);
}

// ---- pack B: [o][k] bf16 rows, LDS-staged coalesced in and out
__global__ __launch_bounds__(256) void pack_b_kernel(
    const float* __restrict__ bw, const float* __restrict__ sw,
    const float* __restrict__ sc, const void* __restrict__ maskp,
    const int* __restrict__ flags, u16* __restrict__ B, float* __restrict__ bias) {
  __shared__ u64 lds64[1120 * 4];  // 35840B as floats for stage, reused as u16 rows
  float* lds_f = (float*)lds64;
  u16* lds_u = (u16*)lds64;

  int t = threadIdx.x, blk = blockIdx.x;
  int id = blk * 256 + t;            // o*512+i
  int o = id >> 9, i = id & 511;
  int i0 = (blk & 1) * 256;

  // coalesced stage of this block's sw chunk: 256 rows x 35 floats
  const float* swb = sw + ((size_t)o * 512 + i0) * 35;
#pragma unroll
  for (int j = 0; j < 35; ++j) lds_f[j * 256 + t] = swb[j * 256 + t];

  int fl = *flags;
  bool mk;
  if (fl & 2)      mk = ((const float*)maskp)[id] != 0.0f;
  else if (fl & 1) mk = ((const unsigned char*)maskp)[id] != 0;
  else             mk = ((const int*)maskp)[id] != 0;

  float s = sc[id];
  __syncthreads();
  float w[35];
#pragma unroll
  for (int c = 0; c < 35; ++c) w[c] = lds_f[t * 35 + c] * s;
  __syncthreads();

  // linear fallback params from endpoint spline values (dx = 2 exactly)
  float ys = (w[0] + 4.0f * w[1] + w[2]) * (1.0f / 6.0f);
  float ye = (w[32] + 4.0f * w[33] + w[34]) * (1.0f / 6.0f);
  float a = (ye - ys) * 0.5f;
  float bl = ys + a;

#pragma unroll
  for (int c = 0; c < 35; ++c) lds_u[t * 36 + c] = f2b(mk ? 0.0f : w[c]);
  lds_u[t * 36 + 35] = 0;

  B[(size_t)o * K_TOT + K_BASE_OFF + i] = f2b(bw[id]);
  B[(size_t)o * K_TOT + K_LIN_OFF + i] = f2b(mk ? a : 0.0f);
  if (mk) atomicAdd(&bias[o], bl);
  __syncthreads();

  // coalesced copy-out: 256*36*2 = 18432B
  u64* dst = (u64*)(B + (size_t)o * K_TOT + (size_t)i0 * C_PAD);
#pragma unroll
  for (int j = 0; j < 9; ++j) dst[j * 256 + t] = lds64[j * 256 + t];
}

// ---- pack A: [b][k] bf16 rows, LDS-staged coalesced out
__global__ __launch_bounds__(256) void pack_a_kernel(const float* __restrict__ x,
                                                     u16* __restrict__ A) {
  __shared__ u64 lds64[2304];  // 256*36 u16 = 18432B
  u16* lds_u = (u16*)lds64;
  int t = threadIdx.x, blk = blockIdx.x;
  int id = blk * 256 + t;            // b*512+i
  int b = id >> 9, i = id & 511;
  int i0 = (blk & 1) * 256;
  float xv = x[id];

  int m = (int)floorf((xv + 1.1875f) * 16.0f);
  float gm = (float)m * 0.0625f - 1.1875f;
  if (xv < gm) { m -= 1; gm -= 0.0625f; }
  else if (xv >= gm + 0.0625f) { m += 1; gm += 0.0625f; }

  bool ok = (m >= 0) && (m <= 37);
  float B0 = 0.f, B1 = 0.f, B2 = 0.f, B3 = 0.f;
  if (ok) {
    float t_ = (xv - gm) * 16.0f;
    float t2 = t_ * t_, t3 = t2 * t_;
    float omt = 1.0f - t_;
    B0 = omt * omt * omt * (1.0f / 6.0f);
    B1 = (3.0f * t3 - 6.0f * t2 + 4.0f) * (1.0f / 6.0f);
    B2 = (-3.0f * t3 + 3.0f * t2 + 3.0f * t_ + 1.0f) * (1.0f / 6.0f);
    B3 = t3 * (1.0f / 6.0f);
  }

#pragma unroll
  for (int c = 0; c < C_PAD; ++c) {
    float v = 0.0f;
    if (ok && c <= 34) {
      if (c == m - 3) v = B0;
      else if (c == m - 2) v = B1;
      else if (c == m - 1) v = B2;
      else if (c == m) v = B3;
    }
    lds_u[t * 36 + c] = f2b(v);
  }

  float sl = xv / (1.0f + __expf(-xv));
  A[(size_t)b * K_TOT + K_BASE_OFF + i] = f2b(sl);
  A[(size_t)b * K_TOT + K_LIN_OFF + i] = f2b(xv);
  __syncthreads();

  u64* dst = (u64*)(A + (size_t)b * K_TOT + (size_t)i0 * C_PAD);
#pragma unroll
  for (int j = 0; j < 9; ++j) dst[j * 256 + t] = lds64[j * 256 + t];
}

// ---- init d_out with per-o bias (atomic-fallback path only)
__global__ void init_out_kernel(const float* __restrict__ bias, float* __restrict__ out) {
  int id = blockIdx.x * blockDim.x + threadIdx.x;
  out[id] = bias[id & 511];
}

// ---- split-K GEMM, 128x128 tile, BK=32, mfma_f32_16x16x32_bf16
// grid 1024 1D; ks = id&31 so all 32 blocks of one ks share an XCD (id mod 8 == ks mod 8)
__global__ __launch_bounds__(256) void gemm_kernel(const u16* __restrict__ A,
                                                   const u16* __restrict__ Bp,
                                                   float* __restrict__ dst,
                                                   int partialMode) {
  __shared__ u16 As[128 * 32];
  __shared__ u16 Bs[128 * 32];
  int t = threadIdx.x;
  int id = blockIdx.x;
  int ks = id & 31, rem = id >> 5;
  int bm = rem & 7, bn = rem >> 3;
  int w = t >> 6, l = t & 63;
  int wm = w & 1, wn = w >> 1;

  floatx4 acc[4][4];
#pragma unroll
  for (int p = 0; p < 4; ++p)
#pragma unroll
    for (int q = 0; q < 4; ++q) acc[p][q] = (floatx4)0.0f;

  int ra = t >> 2;            // staging row 0..63
  int cb = (t & 3) << 3;      // 8-elem (16B) chunk within 32-elem slab
  const u16* Ag = A + (size_t)(bm * 128 + ra) * K_TOT + (size_t)ks * KPS + cb;
  const u16* Bg = Bp + (size_t)(bn * 128 + ra) * K_TOT + (size_t)ks * KPS + cb;
  u16* Asp = &As[ra * 32 + cb];
  u16* Bsp = &Bs[ra * 32 + cb];

  for (int kk = 0; kk < KIT; ++kk) {
    __builtin_amdgcn_global_load_lds((const __attribute__((address_space(1))) void*)Ag,
                                     (__attribute__((address_space(3))) void*)Asp, 16, 0, 0);
    __builtin_amdgcn_global_load_lds((const __attribute__((address_space(1))) void*)(Ag + (size_t)64 * K_TOT),
                                     (__attribute__((address_space(3))) void*)(Asp + 64 * 32), 16, 0, 0);
    __builtin_amdgcn_global_load_lds((const __attribute__((address_space(1))) void*)Bg,
                                     (__attribute__((address_space(3))) void*)Bsp, 16, 0, 0);
    __builtin_amdgcn_global_load_lds((const __attribute__((address_space(1))) void*)(Bg + (size_t)64 * K_TOT),
                                     (__attribute__((address_space(3))) void*)(Bsp + 64 * 32), 16, 0, 0);
    Ag += 32; Bg += 32;
    __syncthreads();

    short8 af[4], bf[4];
    int mr = l & 15;
    int kq = (l >> 4) << 3;
#pragma unroll
    for (int tm = 0; tm < 4; ++tm)
      af[tm] = *(const short8*)&As[(wm * 64 + tm * 16 + mr) * 32 + kq];
#pragma unroll
    for (int tn = 0; tn < 4; ++tn)
      bf[tn] = *(const short8*)&Bs[(wn * 64 + tn * 16 + mr) * 32 + kq];
#pragma unroll
    for (int tm = 0; tm < 4; ++tm)
#pragma unroll
      for (int tn = 0; tn < 4; ++tn)
        acc[tm][tn] = __builtin_amdgcn_mfma_f32_16x16x32_bf16(af[tm], bf[tn], acc[tm][tn], 0, 0, 0);
    __syncthreads();
  }

  // C/D layout: col=lane&15 (n), row=(lane>>4)*4+reg (m)
  int r0 = bm * 128 + wm * 64 + ((l >> 4) << 2);
  int c0 = bn * 128 + wn * 64 + (l & 15);
  if (partialMode) {
    float* P = dst + (size_t)ks * MN;
#pragma unroll
    for (int tm = 0; tm < 4; ++tm)
#pragma unroll
      for (int tn = 0; tn < 4; ++tn)
#pragma unroll
        for (int r = 0; r < 4; ++r)
          P[(size_t)(r0 + tm * 16 + r) * OUT_F + c0 + tn * 16] = acc[tm][tn][r];
  } else {
#pragma unroll
    for (int tm = 0; tm < 4; ++tm)
#pragma unroll
      for (int tn = 0; tn < 4; ++tn)
#pragma unroll
        for (int r = 0; r < 4; ++r)
          atomicAdd(&dst[(size_t)(r0 + tm * 16 + r) * OUT_F + c0 + tn * 16], acc[tm][tn][r]);
  }
}

// ---- reduce 32 partials + bias -> out (float4)
__global__ __launch_bounds__(256) void reduce_kernel(const float* __restrict__ P,
                                                     const float* __restrict__ bias,
                                                     float* __restrict__ out) {
  int id = blockIdx.x * blockDim.x + threadIdx.x;  // 131072 float4s
  floatx4 s = ((const floatx4*)bias)[id & 127];
#pragma unroll
  for (int ks = 0; ks < SPLITS; ++ks) {
    floatx4 p = ((const floatx4*)P)[(size_t)ks * (MN / 4) + id];
    s.x += p.x; s.y += p.y; s.z += p.z; s.w += p.w;
  }
  ((floatx4*)out)[id] = s;
}

extern "C" void kernel_launch(void* const* d_in, const int* in_sizes, int n_in,
                              void* d_out, int out_size, void* d_ws, size_t ws_size,
                              hipStream_t stream) {
  const float* x  = (const float*)d_in[0];
  const float* bw = (const float*)d_in[1];
  const float* sw = (const float*)d_in[2];
  const float* sc = (const float*)d_in[3];
  // d_in[4] = grid: uniform h=1/16 extended knots, constants baked in.
  const void* mask = d_in[5];

  const size_t A_BYTES = (size_t)BATCH * K_TOT * 2;   // 39,845,888
  const size_t B_BYTES = (size_t)OUT_F * K_TOT * 2;   // 19,922,944
  const size_t P_OFF = A_BYTES + B_BYTES + 4096;
  const size_t P_BYTES = (size_t)SPLITS * MN * 4;     // 67,108,864

  char* wsb = (char*)d_ws;
  u16* Apack = (u16*)wsb;
  u16* Bpack = (u16*)(wsb + A_BYTES);
  float* bias = (float*)(wsb + A_BYTES + B_BYTES);
  int* flags = (int*)(wsb + A_BYTES + B_BYTES + 2048);
  float* P = (float*)(wsb + P_OFF);
  int partialMode = (ws_size >= P_OFF + P_BYTES) ? 1 : 0;

  hipMemsetAsync(wsb + A_BYTES + B_BYTES, 0, 4096, stream);
  detect_mask_kernel<<<256, 256, 0, stream>>>((const u32*)mask, flags);
  pack_b_kernel<<<1024, 256, 0, stream>>>(bw, sw, sc, mask, flags, Bpack, bias);
  pack_a_kernel<<<2048, 256, 0, stream>>>(x, Apack);
  if (partialMode) {
    gemm_kernel<<<SPLITS * 32, 256, 0, stream>>>(Apack, Bpack, P, 1);
    reduce_kernel<<<MN / 4 / 256, 256, 0, stream>>>(P, bias, (float*)d_out);
  } else {
    init_out_kernel<<<MN / 256, 256, 0, stream>>>(bias, (float*)d_out);
    gemm_kernel<<<SPLITS * 32, 256, 0, stream>>>(Apack, Bpack, (float*)d_out, 0);
  }
}